// Round 6
// baseline (862.723 us; speedup 1.0000x reference)
//
#include <hip/hip_runtime.h>

typedef unsigned short u16;
typedef unsigned int u32;
typedef float f32x4 __attribute__((ext_vector_type(4)));
typedef __bf16 bf16x8 __attribute__((ext_vector_type(8)));

#define F 256
#define T_OUT 8
#define N_MONO 150000
#define N_CLEAV 100000
#define N_FRAG 80000
#define N_OUT 40000
#define M_CLEAV_PAD 100352   // 392 * 256
#define M_FRAG_PAD 80128     // 313 * 256

static __device__ __forceinline__ u16 f2bf(float f) {
  u32 u = __float_as_uint(f);
  u32 r = (u + 0x7FFFu + ((u >> 16) & 1u)) >> 16;
  return (u16)r;
}
static __device__ __forceinline__ float bf2f(u16 b) {
  return __uint_as_float(((u32)b) << 16);
}
static __device__ __forceinline__ float sigmoidf(float x) {
  return __frcp_rn(1.0f + __expf(-x));
}
static __device__ __forceinline__ float fast_tanh(float x) {
  return 1.0f - 2.0f * __frcp_rn(__expf(2.0f * x) + 1.0f);
}
static __device__ __forceinline__ void async_copy16(const u16* g, const u16* l) {
  __builtin_amdgcn_global_load_lds(
      (const __attribute__((address_space(1))) u32*)g,
      (__attribute__((address_space(3))) u32*)l,
      16, 0, 0);
}

// ---------------- K0: weight cast + bias sum ----------------
__global__ __launch_bounds__(256) void prep_kernel(
    const float* __restrict__ Wih, const float* __restrict__ Whh,
    const float* __restrict__ bih, const float* __restrict__ bhh,
    u16* __restrict__ Wihb, u16* __restrict__ Whhb, float* __restrict__ bias) {
  int i = blockIdx.x * 256 + threadIdx.x;
  if (i < 1024 * 512) Wihb[i] = f2bf(Wih[i]);
  if (i < 1024 * 256) Whhb[i] = f2bf(Whh[i]);
  if (i < 1024) bias[i] = bih[i] + bhh[i];
}

// ---------------- K1: attention pulls -> cleav [N_CLEAV, 512] bf16 --------
__global__ __launch_bounds__(256) void attn_pull(
    const float* __restrict__ feat, const float* __restrict__ WgL,
    const float* __restrict__ WgR, const int* __restrict__ lostS,
    const int* __restrict__ retS, u16* __restrict__ cleav) {
  int wave = threadIdx.x >> 6, lane = threadIdx.x & 63;
  int n = blockIdx.x * 4 + wave;
  if (n >= N_CLEAV) return;
  const float4 wgl = *(const float4*)(WgL + lane * 4);
  const float4 wgr = *(const float4*)(WgR + lane * 4);
  for (int sg = 0; sg < 2; ++sg) {
    const int* src = sg ? retS : lostS;
    float4 wg = sg ? wgr : wgl;
    int4 ridx = *(const int4*)(src + n * 4);
    int r[4] = {ridx.x, ridx.y, ridx.z, ridx.w};
    float4 x[4];
#pragma unroll
    for (int d = 0; d < 4; ++d)
      x[d] = *(const float4*)(feat + (size_t)r[d] * F + lane * 4);
    float logit[4];
#pragma unroll
    for (int d = 0; d < 4; ++d) {
      float p = x[d].x * wg.x + x[d].y * wg.y + x[d].z * wg.z + x[d].w * wg.w;
#pragma unroll
      for (int off = 32; off; off >>= 1) p += __shfl_xor(p, off);
      logit[d] = p;
    }
    float mx = fmaxf(fmaxf(logit[0], logit[1]), fmaxf(logit[2], logit[3]));
    float e0 = __expf(logit[0] - mx), e1 = __expf(logit[1] - mx);
    float e2 = __expf(logit[2] - mx), e3 = __expf(logit[3] - mx);
    float inv = 1.f / (e0 + e1 + e2 + e3);
    float a0 = e0 * inv, a1 = e1 * inv, a2 = e2 * inv, a3 = e3 * inv;
    float4 acc;
    acc.x = a0 * x[0].x + a1 * x[1].x + a2 * x[2].x + a3 * x[3].x;
    acc.y = a0 * x[0].y + a1 * x[1].y + a2 * x[2].y + a3 * x[3].y;
    acc.z = a0 * x[0].z + a1 * x[1].z + a2 * x[2].z + a3 * x[3].z;
    acc.w = a0 * x[0].w + a1 * x[1].w + a2 * x[2].w + a3 * x[3].w;
    u32 lo = (u32)f2bf(acc.x) | ((u32)f2bf(acc.y) << 16);
    u32 hi = (u32)f2bf(acc.z) | ((u32)f2bf(acc.w) << 16);
    *(uint2*)(cleav + (size_t)n * 512 + sg * 256 + lane * 4) = make_uint2(lo, hi);
  }
}

// -------- Weight-stationary GEMM: C[M,1024] = A[M,K] * W[1024,K]^T --------
// Block: 256 thr (4 waves). n-slab = 64 cols of W staged to LDS ONCE
// (K*64*2 B; 64 KB @K=512), then a BARRIER-FREE fully-unrolled K-loop:
// A fragments load straight to VGPR (16 B/lane in MFMA A-layout), B frags
// from the read-only LDS slab (XOR swizzle on (n>>1)&3, conflict-free).
// Wave w owns rows [m0+64w, m0+64w+64) x all 64 slab cols.
// Grid: flat = n * Gpad + g, Gpad % 8 == 0  ->  XCD(flat%8) = g%8: all 16
// n-strips of one m-group share one XCD's L2 (A HBM-fetched once).
// EPI==0: C = acc + bias[n]; EPI==1: C = acc.
template <int EPI, int K>
__global__ __launch_bounds__(256, 3) void gemm_ws(
    const u16* __restrict__ A, const u16* __restrict__ Bw,
    u16* __restrict__ C, const float* __restrict__ bias,
    int Gpad, int gvalid) {
  constexpr int SLABS = K / 32;
  __shared__ u16 Ws[K * 64];  // SLABS x [64 rows x 4 chunks x 8 bf16]

  const int flat = blockIdx.x;
  const int g = flat % Gpad;
  const int nstrip = flat / Gpad;
  if (g >= gvalid) return;
  const int m0 = g * 256;
  const int n0 = nstrip * 64;

  const int tid = threadIdx.x;
  const int lane = tid & 63;
  const int wave = tid >> 6;
  const int quad = lane >> 4;
  const int l16 = lane & 15;

  // ---- stage W slab: thread tid stages row (tid>>2), logical chunk
  // lc = (tid&3)^((tid>>3)&3) of each slab; dest = slab*2048 + tid*8 (u16,
  // = wave-uniform base + lane*16B). Reader: logical chunk q of row n at
  // phys q ^ ((n>>1)&3)  ->  conflict-free (proven r4).
  {
    const int lc = (tid & 3) ^ ((tid >> 3) & 3);
    const u16* src = Bw + (size_t)(n0 + (tid >> 2)) * K + lc * 8;
    const int dst = (tid & ~63) * 8;
#pragma unroll
    for (int s = 0; s < SLABS; ++s)
      async_copy16(src + s * 32, Ws + s * 2048 + dst);
  }
  __syncthreads();

  f32x4 acc[4][4];
#pragma unroll
  for (int i = 0; i < 4; i++)
#pragma unroll
    for (int j = 0; j < 4; j++) acc[i][j] = (f32x4){0.f, 0.f, 0.f, 0.f};

  const u16* Aw = A + (size_t)(m0 + wave * 64) * K + quad * 8;

#pragma unroll
  for (int s = 0; s < SLABS; ++s) {
    bf16x8 af[4], bfr[4];
#pragma unroll
    for (int i = 0; i < 4; i++)
      af[i] = *(const bf16x8*)(Aw + (size_t)(i * 16 + l16) * K + s * 32);
#pragma unroll
    for (int j = 0; j < 4; j++) {
      int n = j * 16 + l16;
      int jp = quad ^ ((n >> 1) & 3);
      bfr[j] = *(const bf16x8*)&Ws[s * 2048 + n * 32 + jp * 8];
    }
#pragma unroll
    for (int i = 0; i < 4; i++)
#pragma unroll
      for (int j = 0; j < 4; j++)
        acc[i][j] = __builtin_amdgcn_mfma_f32_16x16x32_bf16(af[i], bfr[j], acc[i][j], 0, 0, 0);
  }

  // epilogue: C/D layout col=lane&15, row=quad*4+reg
#pragma unroll
  for (int i = 0; i < 4; i++) {
    int mbase = m0 + wave * 64 + i * 16 + quad * 4;
#pragma unroll
    for (int j = 0; j < 4; j++) {
      int n = n0 + j * 16 + l16;
      float badd = (EPI == 0) ? bias[n] : 0.f;
#pragma unroll
      for (int r = 0; r < 4; r++) {
        int m = mbase + r;
        C[(size_t)m * 1024 + n] = f2bf(acc[i][j][r] + badd);
      }
    }
  }
}

// ---------------- K3: LSTM step 1, wave-per-fragment ----------------------
__global__ __launch_bounds__(256) void lstm_step1(
    const u16* __restrict__ P, const int* __restrict__ join,
    u16* __restrict__ h1, u16* __restrict__ c1) {
  int wave = threadIdx.x >> 6, lane = threadIdx.x & 63;
  int m = blockIdx.x * 4 + wave;
  if (m >= N_FRAG) return;
  int j0 = join[2 * m];
  const u16* row = P + (size_t)j0 * 1024 + lane * 4;
  ushort4 iv = *(const ushort4*)(row);
  ushort4 gv = *(const ushort4*)(row + 512);
  ushort4 ov = *(const ushort4*)(row + 768);
  const u16* ivp = (const u16*)&iv;
  const u16* gvp = (const u16*)&gv;
  const u16* ovp = (const u16*)&ov;
  ushort4 h4, c4;
  u16* h4p = (u16*)&h4;
  u16* c4p = (u16*)&c4;
#pragma unroll
  for (int k = 0; k < 4; k++) {
    float c = sigmoidf(bf2f(ivp[k])) * fast_tanh(bf2f(gvp[k]));
    float hv = sigmoidf(bf2f(ovp[k])) * fast_tanh(c);
    h4p[k] = f2bf(hv);
    c4p[k] = f2bf(c);
  }
  *(ushort4*)(h1 + (size_t)m * 256 + lane * 4) = h4;
  *(ushort4*)(c1 + (size_t)m * 256 + lane * 4) = c4;
}

// ------- K5: LSTM step 2 + attention over {h1,h2} + output head -----------
__global__ __launch_bounds__(256) void lstm_step2_attn_out(
    const u16* __restrict__ G2, const u16* __restrict__ P,
    const int* __restrict__ join, const u16* __restrict__ c1,
    const u16* __restrict__ h1b, const float* __restrict__ Wg,
    const float* __restrict__ Wout, const float* __restrict__ bout,
    float* __restrict__ frag_out) {
  int wave = threadIdx.x >> 6, lane = threadIdx.x & 63;
  int m = blockIdx.x * 4 + wave;
  if (m >= N_FRAG) return;
  int j1 = join[2 * m + 1];
  const u16* row = G2 + (size_t)m * 1024 + lane * 4;
  const u16* prow = P + (size_t)j1 * 1024 + lane * 4;
  ushort4 iv = *(const ushort4*)(row);
  ushort4 fv = *(const ushort4*)(row + 256);
  ushort4 gv = *(const ushort4*)(row + 512);
  ushort4 ov = *(const ushort4*)(row + 768);
  ushort4 pi = *(const ushort4*)(prow);
  ushort4 pf = *(const ushort4*)(prow + 256);
  ushort4 pg = *(const ushort4*)(prow + 512);
  ushort4 po = *(const ushort4*)(prow + 768);
  ushort4 c4 = *(const ushort4*)(c1 + (size_t)m * 256 + lane * 4);
  ushort4 h4 = *(const ushort4*)(h1b + (size_t)m * 256 + lane * 4);
  float4 wg = *(const float4*)(Wg + lane * 4);
  const u16* ivp = (const u16*)&iv; const u16* pip = (const u16*)&pi;
  const u16* fvp = (const u16*)&fv; const u16* pfp = (const u16*)&pf;
  const u16* gvp = (const u16*)&gv; const u16* pgp = (const u16*)&pg;
  const u16* ovp = (const u16*)&ov; const u16* pop = (const u16*)&po;
  const u16* c4p = (const u16*)&c4;
  const u16* h4p = (const u16*)&h4;
  const float* wgp = (const float*)&wg;

  float h1v[4], h2v[4];
  float p1 = 0.f, p2 = 0.f;
#pragma unroll
  for (int k = 0; k < 4; k++) {
    float gi = bf2f(ivp[k]) + bf2f(pip[k]);
    float gf = bf2f(fvp[k]) + bf2f(pfp[k]);
    float gg = bf2f(gvp[k]) + bf2f(pgp[k]);
    float go = bf2f(ovp[k]) + bf2f(pop[k]);
    float c2 = sigmoidf(gf) * bf2f(c4p[k]) + sigmoidf(gi) * fast_tanh(gg);
    float h2 = sigmoidf(go) * fast_tanh(c2);
    h2v[k] = h2;
    h1v[k] = bf2f(h4p[k]);
    p1 += h1v[k] * wgp[k];
    p2 += h2 * wgp[k];
  }
#pragma unroll
  for (int off = 32; off; off >>= 1) {
    p1 += __shfl_xor(p1, off);
    p2 += __shfl_xor(p2, off);
  }
  float mx = fmaxf(p1, p2);
  float e1 = __expf(p1 - mx), e2 = __expf(p2 - mx);
  float inv = __frcp_rn(e1 + e2);
  float a1 = e1 * inv, a2 = e2 * inv;

  float acc[8];
#pragma unroll
  for (int t = 0; t < 8; t++) acc[t] = 0.f;
#pragma unroll
  for (int k = 0; k < 4; k++) {
    float frag = a1 * h1v[k] + a2 * h2v[k];
    int h = lane * 4 + k;
    float4 w0 = *(const float4*)(Wout + h * 8);
    float4 w1 = *(const float4*)(Wout + h * 8 + 4);
    acc[0] += frag * w0.x; acc[1] += frag * w0.y;
    acc[2] += frag * w0.z; acc[3] += frag * w0.w;
    acc[4] += frag * w1.x; acc[5] += frag * w1.y;
    acc[6] += frag * w1.z; acc[7] += frag * w1.w;
  }
#pragma unroll
  for (int off = 32; off; off >>= 1)
#pragma unroll
    for (int t = 0; t < 8; t++) acc[t] += __shfl_xor(acc[t], off);
  if (lane == 0) {
    float4 o0, o1;
    o0.x = fmaxf(acc[0] + bout[0], 0.f);
    o0.y = fmaxf(acc[1] + bout[1], 0.f);
    o0.z = fmaxf(acc[2] + bout[2], 0.f);
    o0.w = fmaxf(acc[3] + bout[3], 0.f);
    o1.x = fmaxf(acc[4] + bout[4], 0.f);
    o1.y = fmaxf(acc[5] + bout[5], 0.f);
    o1.z = fmaxf(acc[6] + bout[6], 0.f);
    o1.w = fmaxf(acc[7] + bout[7], 0.f);
    *(float4*)(frag_out + (size_t)m * 8) = o0;
    *(float4*)(frag_out + (size_t)m * 8 + 4) = o1;
  }
}

// ---------------- K6: combine scatter-sum ---------------------------------
__global__ __launch_bounds__(256) void scatter_sum(
    const float* __restrict__ frag_out, const int* __restrict__ comb,
    float* __restrict__ out) {
  int tid = blockIdx.x * 256 + threadIdx.x;
  if (tid >= N_OUT * 8) return;
  int n = tid >> 3, t = tid & 7;
  float s = 0.f;
#pragma unroll
  for (int d = 0; d < 4; d++) {
    int f = comb[n * 4 + d];
    s += frag_out[(size_t)f * 8 + t];
  }
  out[tid] = s;
}

extern "C" void kernel_launch(void* const* d_in, const int* in_sizes, int n_in,
                              void* d_out, int out_size, void* d_ws, size_t ws_size,
                              hipStream_t stream) {
  const float* feature = (const float*)d_in[0];
  const float* WgL = (const float*)d_in[1];
  const float* WgR = (const float*)d_in[2];
  const float* Wih = (const float*)d_in[3];
  const float* Whh = (const float*)d_in[4];
  const float* bih = (const float*)d_in[5];
  const float* bhh = (const float*)d_in[6];
  const float* Wgf = (const float*)d_in[7];
  const float* Wout = (const float*)d_in[8];
  const float* bout = (const float*)d_in[9];
  const int* lostS = (const int*)d_in[10];
  const int* retS = (const int*)d_in[11];
  const int* joinS = (const int*)d_in[12];
  const int* combS = (const int*)d_in[13];
  float* out = (float*)d_out;

  char* ws = (char*)d_ws;
  size_t off = 0;
  auto alloc = [&](size_t bytes) -> char* {
    char* p = ws + off;
    off = (off + bytes + 255) & ~(size_t)255;
    return p;
  };
  u16* Wihb = (u16*)alloc((size_t)1024 * 512 * 2);
  u16* Whhb = (u16*)alloc((size_t)1024 * 256 * 2);
  float* bias = (float*)alloc(1024 * 4);
  u16* P = (u16*)alloc((size_t)M_CLEAV_PAD * 1024 * 2);
  u16* h1 = (u16*)alloc((size_t)M_FRAG_PAD * 256 * 2);
  u16* c1 = (u16*)alloc((size_t)N_FRAG * 256 * 2);
  float* frag_out = (float*)alloc((size_t)N_FRAG * 8 * 4);
  char* uni = alloc((size_t)M_CLEAV_PAD * 1024 * 2);  // cleav then gates2
  u16* cleav = (u16*)uni;
  u16* gates2 = (u16*)uni;

  prep_kernel<<<2048, 256, 0, stream>>>(Wih, Whh, bih, bhh, Wihb, Whhb, bias);
  attn_pull<<<N_CLEAV / 4, 256, 0, stream>>>(feature, WgL, WgR, lostS, retS, cleav);
  // GEMM-1: 392 m-groups (256 rows) x 16 n-strips; Gpad=392 (392%8==0)
  gemm_ws<0, 512><<<16 * 392, 256, 0, stream>>>(cleav, Wihb, P, bias, 392, 392);
  lstm_step1<<<N_FRAG / 4, 256, 0, stream>>>(P, joinS, h1, c1);
  // GEMM-2: 313 valid m-groups, Gpad=320 (tail exits)
  gemm_ws<1, 256><<<16 * 320, 256, 0, stream>>>(h1, Whhb, gates2, nullptr, 320, 313);
  lstm_step2_attn_out<<<N_FRAG / 4, 256, 0, stream>>>(
      gates2, P, joinS, c1, h1, Wgf, Wout, bout, frag_out);
  scatter_sum<<<(N_OUT * 8 + 255) / 256, 256, 0, stream>>>(frag_out, combS, out);
}